// Round 1
// baseline (3661.931 us; speedup 1.0000x reference)
//
#include <hip/hip_runtime.h>

typedef _Float16 f16;
typedef __attribute__((ext_vector_type(8))) _Float16 f16x8;
typedef __attribute__((ext_vector_type(4))) _Float16 f16x4;
typedef __attribute__((ext_vector_type(4))) float f32x4;

#define CC 128
#define K2 256
#define BN_EPS 1e-5f

__device__ __forceinline__ float elu(float v) {
    return v > 0.f ? v : __expf(v) - 1.f;
}

// ---------------------------------------------------------------------------
// Edge GEMM: h[e,:] = concat(x[row[e]], edge_attr[e]) @ w1.T + b1
// Stores h as f16 to ws, accumulates per-channel sum/sumsq for BN1.
// Block = 256 threads (4 waves). Tile = 32 edges x 128 out-channels.
// Wave w owns output columns [32w, 32w+32); holds B frags in registers.
// ---------------------------------------------------------------------------
__global__ __launch_bounds__(256)
void edge_gemm(const float* __restrict__ x, const int* __restrict__ rowidx,
               const float* __restrict__ eattr, const float* __restrict__ w1,
               const float* __restrict__ b1,
               f16* __restrict__ hbuf, float* __restrict__ sum1,
               float* __restrict__ sq1, int E, int nTiles)
{
    __shared__ __align__(16) f16 a_lds[32 * 264];   // 32 rows x 256 f16, +8 pad
    __shared__ __align__(16) f16 h_lds[32 * 136];   // 32 rows x 128 f16, +8 pad
    __shared__ int rows_s[32];

    const int tid  = threadIdx.x;
    const int lane = tid & 63;
    const int wave = tid >> 6;
    const int quad = lane >> 4;
    const int l16  = lane & 15;
    const int n_off = wave * 32;

    // Preload B fragments: B[k][n] = w1[n][k]  (w1 is [128][256] row-major)
    f16x8 bfrag[8][2];
    float bias[2];
    #pragma unroll
    for (int ns = 0; ns < 2; ++ns) {
        int n = n_off + ns * 16 + l16;
        bias[ns] = b1[n];
        #pragma unroll
        for (int kk = 0; kk < 8; ++kk) {
            const float* wr = w1 + n * K2 + kk * 32 + quad * 8;
            f16x8 f;
            #pragma unroll
            for (int j = 0; j < 8; ++j) f[j] = (f16)wr[j];
            bfrag[kk][ns] = f;
        }
    }

    float st_s[2] = {0.f, 0.f};
    float st_q[2] = {0.f, 0.f};
    const f32x4 zero4 = {0.f, 0.f, 0.f, 0.f};

    for (int t = blockIdx.x; t < nTiles; t += gridDim.x) {
        const int e0 = t * 32;
        if (tid < 32) rows_s[tid] = (e0 + tid < E) ? rowidx[e0 + tid] : 0;
        __syncthreads();

        // Stage A tile: 32 rows x 256 cols (fp32 -> f16)
        #pragma unroll
        for (int i = 0; i < 8; ++i) {
            int chunk = tid + i * 256;
            int r  = chunk >> 6;
            int cc = (chunk & 63) * 4;
            float4 v = {0.f, 0.f, 0.f, 0.f};
            if (e0 + r < E) {
                const float* src = (cc < CC)
                    ? x + (size_t)rows_s[r] * CC + cc
                    : eattr + (size_t)(e0 + r) * CC + (cc - CC);
                v = *(const float4*)src;
            }
            f16 tmp[4] = {(f16)v.x, (f16)v.y, (f16)v.z, (f16)v.w};
            *(f16x4*)&a_lds[r * 264 + cc] = *(f16x4*)tmp;
        }
        __syncthreads();

        f32x4 acc[2][2];
        acc[0][0] = zero4; acc[0][1] = zero4; acc[1][0] = zero4; acc[1][1] = zero4;

        #pragma unroll
        for (int kk = 0; kk < 8; ++kk) {
            int kb = kk * 32 + quad * 8;
            f16x8 af0 = *(f16x8*)&a_lds[l16 * 264 + kb];
            f16x8 af1 = *(f16x8*)&a_lds[(16 + l16) * 264 + kb];
            acc[0][0] = __builtin_amdgcn_mfma_f32_16x16x32_f16(af0, bfrag[kk][0], acc[0][0], 0, 0, 0);
            acc[0][1] = __builtin_amdgcn_mfma_f32_16x16x32_f16(af0, bfrag[kk][1], acc[0][1], 0, 0, 0);
            acc[1][0] = __builtin_amdgcn_mfma_f32_16x16x32_f16(af1, bfrag[kk][0], acc[1][0], 0, 0, 0);
            acc[1][1] = __builtin_amdgcn_mfma_f32_16x16x32_f16(af1, bfrag[kk][1], acc[1][1], 0, 0, 0);
        }

        // Bias + stats + stage h tile into LDS (C/D layout: col=lane&15, row=quad*4+reg)
        #pragma unroll
        for (int ms = 0; ms < 2; ++ms) {
            #pragma unroll
            for (int ns = 0; ns < 2; ++ns) {
                int col = n_off + ns * 16 + l16;
                #pragma unroll
                for (int r = 0; r < 4; ++r) {
                    int rl = ms * 16 + quad * 4 + r;
                    float v = acc[ms][ns][r] + bias[ns];
                    if (e0 + rl < E) { st_s[ns] += v; st_q[ns] += v * v; }
                    h_lds[rl * 136 + col] = (f16)v;
                }
            }
        }
        __syncthreads();

        // Coalesced store of the h tile (f16x8 per thread x2)
        #pragma unroll
        for (int j = 0; j < 2; ++j) {
            int chunk = tid + j * 256;
            int r  = chunk >> 4;
            int cc = (chunk & 15) * 8;
            if (e0 + r < E) {
                f16x8 v = *(f16x8*)&h_lds[r * 136 + cc];
                *(f16x8*)&hbuf[(size_t)(e0 + r) * CC + cc] = v;
            }
        }
    }

    // Reduce stats across quads, one atomic per channel per wave
    #pragma unroll
    for (int ns = 0; ns < 2; ++ns) {
        float s = st_s[ns], q = st_q[ns];
        s += __shfl_xor(s, 16, 64); q += __shfl_xor(q, 16, 64);
        s += __shfl_xor(s, 32, 64); q += __shfl_xor(q, 32, 64);
        if (lane < 16) {
            int c = n_off + ns * 16 + lane;
            atomicAdd(&sum1[c], s);
            atomicAdd(&sq1[c], q);
        }
    }
}

// ---------------------------------------------------------------------------
__global__ void finalize_stats(const float* __restrict__ sum, const float* __restrict__ sq,
                               const float* __restrict__ bnw, const float* __restrict__ bnb,
                               float* __restrict__ scale, float* __restrict__ shift,
                               float invN)
{
    int c = threadIdx.x;
    float mu  = sum[c] * invN;
    float var = sq[c] * invN - mu * mu;
    float sc  = bnw[c] * rsqrtf(var + BN_EPS);
    scale[c] = sc;
    shift[c] = bnb[c] - mu * sc;
}

// ---------------------------------------------------------------------------
// Scatter: y = elu(bn(h)); agg[col[e]] += y; cnt[col[e]] += 1
// One thread per (edge, 8-channel group).
// ---------------------------------------------------------------------------
__global__ __launch_bounds__(256)
void scatter_edges(const f16* __restrict__ hbuf, const int* __restrict__ colidx,
                   const float* __restrict__ scale, const float* __restrict__ shift,
                   float* __restrict__ agg, float* __restrict__ cnt, int E)
{
    __shared__ float sc_s[CC], sh_s[CC];
    int tid = threadIdx.x;
    if (tid < CC) { sc_s[tid] = scale[tid]; sh_s[tid] = shift[tid]; }
    __syncthreads();

    int g = blockIdx.x * 256 + tid;
    int e = g >> 4;
    if (e >= E) return;
    int part  = g & 15;
    int cbase = part * 8;

    f16x8 hv = *(const f16x8*)&hbuf[(size_t)e * CC + cbase];
    int node = colidx[e];
    float* dst = agg + (size_t)node * CC + cbase;
    #pragma unroll
    for (int j = 0; j < 8; ++j) {
        float v = elu((float)hv[j] * sc_s[cbase + j] + sh_s[cbase + j]);
        atomicAdd(&dst[j], v);
    }
    if (part == 0) atomicAdd(&cnt[node], 1.0f);
}

// ---------------------------------------------------------------------------
// Node GEMM: out_pre[i,:] = concat(x[i], agg[i]/max(cnt,1)) @ w2.T + b2
// Same MFMA structure; writes fp32 pre-BN to d_out, accumulates BN2 stats.
// ---------------------------------------------------------------------------
__global__ __launch_bounds__(256)
void node_gemm(const float* __restrict__ x, const float* __restrict__ agg,
               const float* __restrict__ cnt, const float* __restrict__ w2,
               const float* __restrict__ b2,
               float* __restrict__ outp, float* __restrict__ sum2,
               float* __restrict__ sq2, int Nn, int nTiles)
{
    __shared__ __align__(16) f16 a_lds[32 * 264];
    __shared__ __align__(16) float f_lds[32 * 132];

    const int tid  = threadIdx.x;
    const int lane = tid & 63;
    const int wave = tid >> 6;
    const int quad = lane >> 4;
    const int l16  = lane & 15;
    const int n_off = wave * 32;

    f16x8 bfrag[8][2];
    float bias[2];
    #pragma unroll
    for (int ns = 0; ns < 2; ++ns) {
        int n = n_off + ns * 16 + l16;
        bias[ns] = b2[n];
        #pragma unroll
        for (int kk = 0; kk < 8; ++kk) {
            const float* wr = w2 + n * K2 + kk * 32 + quad * 8;
            f16x8 f;
            #pragma unroll
            for (int j = 0; j < 8; ++j) f[j] = (f16)wr[j];
            bfrag[kk][ns] = f;
        }
    }

    float st_s[2] = {0.f, 0.f};
    float st_q[2] = {0.f, 0.f};
    const f32x4 zero4 = {0.f, 0.f, 0.f, 0.f};

    for (int t = blockIdx.x; t < nTiles; t += gridDim.x) {
        const int i0 = t * 32;
        __syncthreads();

        #pragma unroll
        for (int i = 0; i < 8; ++i) {
            int chunk = tid + i * 256;
            int r  = chunk >> 6;
            int cc = (chunk & 63) * 4;
            int node = i0 + r;
            float4 v = {0.f, 0.f, 0.f, 0.f};
            if (node < Nn) {
                if (cc < CC) {
                    v = *(const float4*)(x + (size_t)node * CC + cc);
                } else {
                    float rc = 1.f / fmaxf(cnt[node], 1.f);
                    float4 a = *(const float4*)(agg + (size_t)node * CC + (cc - CC));
                    v.x = a.x * rc; v.y = a.y * rc; v.z = a.z * rc; v.w = a.w * rc;
                }
            }
            f16 tmp[4] = {(f16)v.x, (f16)v.y, (f16)v.z, (f16)v.w};
            *(f16x4*)&a_lds[r * 264 + cc] = *(f16x4*)tmp;
        }
        __syncthreads();

        f32x4 acc[2][2];
        acc[0][0] = zero4; acc[0][1] = zero4; acc[1][0] = zero4; acc[1][1] = zero4;

        #pragma unroll
        for (int kk = 0; kk < 8; ++kk) {
            int kb = kk * 32 + quad * 8;
            f16x8 af0 = *(f16x8*)&a_lds[l16 * 264 + kb];
            f16x8 af1 = *(f16x8*)&a_lds[(16 + l16) * 264 + kb];
            acc[0][0] = __builtin_amdgcn_mfma_f32_16x16x32_f16(af0, bfrag[kk][0], acc[0][0], 0, 0, 0);
            acc[0][1] = __builtin_amdgcn_mfma_f32_16x16x32_f16(af0, bfrag[kk][1], acc[0][1], 0, 0, 0);
            acc[1][0] = __builtin_amdgcn_mfma_f32_16x16x32_f16(af1, bfrag[kk][0], acc[1][0], 0, 0, 0);
            acc[1][1] = __builtin_amdgcn_mfma_f32_16x16x32_f16(af1, bfrag[kk][1], acc[1][1], 0, 0, 0);
        }

        #pragma unroll
        for (int ms = 0; ms < 2; ++ms) {
            #pragma unroll
            for (int ns = 0; ns < 2; ++ns) {
                int col = n_off + ns * 16 + l16;
                #pragma unroll
                for (int r = 0; r < 4; ++r) {
                    int rl = ms * 16 + quad * 4 + r;
                    float v = acc[ms][ns][r] + bias[ns];
                    if (i0 + rl < Nn) { st_s[ns] += v; st_q[ns] += v * v; }
                    f_lds[rl * 132 + col] = v;
                }
            }
        }
        __syncthreads();

        #pragma unroll
        for (int j = 0; j < 4; ++j) {
            int chunk = tid + j * 256;
            int r  = chunk >> 5;
            int cc = (chunk & 31) * 4;
            if (i0 + r < Nn) {
                float4 v = *(float4*)&f_lds[r * 132 + cc];
                *(float4*)&outp[(size_t)(i0 + r) * CC + cc] = v;
            }
        }
    }

    #pragma unroll
    for (int ns = 0; ns < 2; ++ns) {
        float s = st_s[ns], q = st_q[ns];
        s += __shfl_xor(s, 16, 64); q += __shfl_xor(q, 16, 64);
        s += __shfl_xor(s, 32, 64); q += __shfl_xor(q, 32, 64);
        if (lane < 16) {
            int c = n_off + ns * 16 + lane;
            atomicAdd(&sum2[c], s);
            atomicAdd(&sq2[c], q);
        }
    }
}

// ---------------------------------------------------------------------------
__global__ __launch_bounds__(256)
void bn_elu_out(float* __restrict__ out, const float* __restrict__ scale,
                const float* __restrict__ shift, int total4)
{
    int g = blockIdx.x * 256 + threadIdx.x;
    if (g >= total4) return;
    int cb = (g & 31) * 4;
    float4 v = ((const float4*)out)[g];
    v.x = elu(v.x * scale[cb + 0] + shift[cb + 0]);
    v.y = elu(v.y * scale[cb + 1] + shift[cb + 1]);
    v.z = elu(v.z * scale[cb + 2] + shift[cb + 2]);
    v.w = elu(v.w * scale[cb + 3] + shift[cb + 3]);
    ((float4*)out)[g] = v;
}

// ---------------------------------------------------------------------------
extern "C" void kernel_launch(void* const* d_in, const int* in_sizes, int n_in,
                              void* d_out, int out_size, void* d_ws, size_t ws_size,
                              hipStream_t stream)
{
    const float* x     = (const float*)d_in[0];
    const int*   eidx  = (const int*)d_in[1];
    const float* eattr = (const float*)d_in[2];
    // d_in[3] = u, d_in[4] = batch : unused by the reference
    const float* w1   = (const float*)d_in[5];
    const float* b1   = (const float*)d_in[6];
    const float* bn1w = (const float*)d_in[7];
    const float* bn1b = (const float*)d_in[8];
    const float* w2   = (const float*)d_in[9];
    const float* b2   = (const float*)d_in[10];
    const float* bn2w = (const float*)d_in[11];
    const float* bn2b = (const float*)d_in[12];

    const int Nn = in_sizes[0] / CC;   // 50000
    const int E  = in_sizes[1] / 2;    // 800000
    const int* rowi = eidx;
    const int* coli = eidx + E;

    char* ws = (char*)d_ws;
    f16*   hbuf = (f16*)ws;                 size_t off = (size_t)E * CC * sizeof(f16);
    float* agg  = (float*)(ws + off);       off += (size_t)Nn * CC * sizeof(float);
    float* cnt  = (float*)(ws + off);       off += (size_t)Nn * sizeof(float);
    float* sum1 = (float*)(ws + off);
    float* sq1  = sum1 + CC;
    float* sc1  = sum1 + 2 * CC;
    float* sh1  = sum1 + 3 * CC;
    float* sum2 = sum1 + 4 * CC;
    float* sq2  = sum1 + 5 * CC;
    float* sc2  = sum1 + 6 * CC;
    float* sh2  = sum1 + 7 * CC;

    // Zero accumulators (ws is re-poisoned to 0xAA before every call)
    hipMemsetAsync(agg, 0, (size_t)Nn * CC * sizeof(float) + Nn * sizeof(float), stream);
    hipMemsetAsync(sum1, 0, 8 * CC * sizeof(float), stream);

    const int nT1 = (E + 31) / 32;
    edge_gemm<<<1024, 256, 0, stream>>>(x, rowi, eattr, w1, b1, hbuf, sum1, sq1, E, nT1);
    finalize_stats<<<1, CC, 0, stream>>>(sum1, sq1, bn1w, bn1b, sc1, sh1, 1.f / (float)E);

    const int nBs = (E * 16 + 255) / 256;
    scatter_edges<<<nBs, 256, 0, stream>>>(hbuf, coli, sc1, sh1, agg, cnt, E);

    const int nT2 = (Nn + 31) / 32;
    node_gemm<<<nT2, 256, 0, stream>>>(x, agg, cnt, w2, b2, (float*)d_out, sum2, sq2, Nn, nT2);
    finalize_stats<<<1, CC, 0, stream>>>(sum2, sq2, bn2w, bn2b, sc2, sh2, 1.f / (float)Nn);

    const int t4 = Nn * CC / 4;
    bn_elu_out<<<(t4 + 255) / 256, 256, 0, stream>>>((float*)d_out, sc2, sh2, t4);
}

// Round 2
// 1109.723 us; speedup vs baseline: 3.2999x; 3.2999x over previous
//
#include <hip/hip_runtime.h>

typedef _Float16 f16;
typedef __attribute__((ext_vector_type(8))) _Float16 f16x8;
typedef __attribute__((ext_vector_type(4))) _Float16 f16x4;
typedef __attribute__((ext_vector_type(2))) _Float16 f16x2;
typedef __attribute__((ext_vector_type(4))) float f32x4;

#define CC 128
#define K2 256
#define BN_EPS 1e-5f

__device__ __forceinline__ float elu(float v) {
    return v > 0.f ? v : __expf(v) - 1.f;
}

// ---------------------------------------------------------------------------
// Edge GEMM: h[e,:] = concat(x[row[e]], edge_attr[e]) @ w1.T + b1
// Stores h as f16 to ws, accumulates per-channel sum/sumsq for BN1.
// ---------------------------------------------------------------------------
__global__ __launch_bounds__(256)
void edge_gemm(const float* __restrict__ x, const int* __restrict__ rowidx,
               const float* __restrict__ eattr, const float* __restrict__ w1,
               const float* __restrict__ b1,
               f16* __restrict__ hbuf, float* __restrict__ sum1,
               float* __restrict__ sq1, int E, int nTiles)
{
    __shared__ __align__(16) f16 a_lds[32 * 264];   // 32 rows x 256 f16, +8 pad
    __shared__ __align__(16) f16 h_lds[32 * 136];   // 32 rows x 128 f16, +8 pad
    __shared__ int rows_s[32];

    const int tid  = threadIdx.x;
    const int lane = tid & 63;
    const int wave = tid >> 6;
    const int quad = lane >> 4;
    const int l16  = lane & 15;
    const int n_off = wave * 32;

    // Preload B fragments: B[k][n] = w1[n][k]  (w1 is [128][256] row-major)
    f16x8 bfrag[8][2];
    float bias[2];
    #pragma unroll
    for (int ns = 0; ns < 2; ++ns) {
        int n = n_off + ns * 16 + l16;
        bias[ns] = b1[n];
        #pragma unroll
        for (int kk = 0; kk < 8; ++kk) {
            const float* wr = w1 + n * K2 + kk * 32 + quad * 8;
            f16x8 f;
            #pragma unroll
            for (int j = 0; j < 8; ++j) f[j] = (f16)wr[j];
            bfrag[kk][ns] = f;
        }
    }

    float st_s[2] = {0.f, 0.f};
    float st_q[2] = {0.f, 0.f};
    const f32x4 zero4 = {0.f, 0.f, 0.f, 0.f};

    for (int t = blockIdx.x; t < nTiles; t += gridDim.x) {
        const int e0 = t * 32;
        if (tid < 32) rows_s[tid] = (e0 + tid < E) ? rowidx[e0 + tid] : 0;
        __syncthreads();

        // Stage A tile: 32 rows x 256 cols (fp32 -> f16)
        #pragma unroll
        for (int i = 0; i < 8; ++i) {
            int chunk = tid + i * 256;
            int r  = chunk >> 6;
            int cc = (chunk & 63) * 4;
            float4 v = {0.f, 0.f, 0.f, 0.f};
            if (e0 + r < E) {
                const float* src = (cc < CC)
                    ? x + (size_t)rows_s[r] * CC + cc
                    : eattr + (size_t)(e0 + r) * CC + (cc - CC);
                v = *(const float4*)src;
            }
            f16 tmp[4] = {(f16)v.x, (f16)v.y, (f16)v.z, (f16)v.w};
            *(f16x4*)&a_lds[r * 264 + cc] = *(f16x4*)tmp;
        }
        __syncthreads();

        f32x4 acc[2][2];
        acc[0][0] = zero4; acc[0][1] = zero4; acc[1][0] = zero4; acc[1][1] = zero4;

        #pragma unroll
        for (int kk = 0; kk < 8; ++kk) {
            int kb = kk * 32 + quad * 8;
            f16x8 af0 = *(f16x8*)&a_lds[l16 * 264 + kb];
            f16x8 af1 = *(f16x8*)&a_lds[(16 + l16) * 264 + kb];
            acc[0][0] = __builtin_amdgcn_mfma_f32_16x16x32_f16(af0, bfrag[kk][0], acc[0][0], 0, 0, 0);
            acc[0][1] = __builtin_amdgcn_mfma_f32_16x16x32_f16(af0, bfrag[kk][1], acc[0][1], 0, 0, 0);
            acc[1][0] = __builtin_amdgcn_mfma_f32_16x16x32_f16(af1, bfrag[kk][0], acc[1][0], 0, 0, 0);
            acc[1][1] = __builtin_amdgcn_mfma_f32_16x16x32_f16(af1, bfrag[kk][1], acc[1][1], 0, 0, 0);
        }

        // Bias + stats + stage h tile into LDS (C/D layout: col=lane&15, row=quad*4+reg)
        #pragma unroll
        for (int ms = 0; ms < 2; ++ms) {
            #pragma unroll
            for (int ns = 0; ns < 2; ++ns) {
                int col = n_off + ns * 16 + l16;
                #pragma unroll
                for (int r = 0; r < 4; ++r) {
                    int rl = ms * 16 + quad * 4 + r;
                    float v = acc[ms][ns][r] + bias[ns];
                    if (e0 + rl < E) { st_s[ns] += v; st_q[ns] += v * v; }
                    h_lds[rl * 136 + col] = (f16)v;
                }
            }
        }
        __syncthreads();

        // Coalesced store of the h tile (f16x8 per thread x2)
        #pragma unroll
        for (int j = 0; j < 2; ++j) {
            int chunk = tid + j * 256;
            int r  = chunk >> 4;
            int cc = (chunk & 15) * 8;
            if (e0 + r < E) {
                f16x8 v = *(f16x8*)&h_lds[r * 136 + cc];
                *(f16x8*)&hbuf[(size_t)(e0 + r) * CC + cc] = v;
            }
        }
    }

    // Reduce stats across quads, one atomic per channel per wave
    #pragma unroll
    for (int ns = 0; ns < 2; ++ns) {
        float s = st_s[ns], q = st_q[ns];
        s += __shfl_xor(s, 16, 64); q += __shfl_xor(q, 16, 64);
        s += __shfl_xor(s, 32, 64); q += __shfl_xor(q, 32, 64);
        if (lane < 16) {
            int c = n_off + ns * 16 + lane;
            atomicAdd(&sum1[c], s);
            atomicAdd(&sq1[c], q);
        }
    }
}

// ---------------------------------------------------------------------------
__global__ void finalize_stats(const float* __restrict__ sum, const float* __restrict__ sq,
                               const float* __restrict__ bnw, const float* __restrict__ bnb,
                               float* __restrict__ scale, float* __restrict__ shift,
                               float invN)
{
    int c = threadIdx.x;
    float mu  = sum[c] * invN;
    float var = sq[c] * invN - mu * mu;
    float sc  = bnw[c] * rsqrtf(var + BN_EPS);
    scale[c] = sc;
    shift[c] = bnb[c] - mu * sc;
}

// ---------------------------------------------------------------------------
// CSR build: histogram -> single-block scan -> fill
// ---------------------------------------------------------------------------
__global__ __launch_bounds__(256)
void k_hist(const int* __restrict__ colidx, int* __restrict__ cnt_i, int E)
{
    int e = blockIdx.x * 256 + threadIdx.x;
    if (e < E) atomicAdd(&cnt_i[colidx[e]], 1);
}

__global__ __launch_bounds__(1024)
void k_scan(const int* __restrict__ cnt_i, int* __restrict__ start,
            int* __restrict__ cursor, int Nn)
{
    __shared__ int wsum[16];
    const int tid  = threadIdx.x;
    const int lane = tid & 63;
    const int wid  = tid >> 6;
    int carry = 0;
    const int nChunks = (Nn + 1023) / 1024;
    for (int c = 0; c < nChunks; ++c) {
        int i = c * 1024 + tid;
        int v = (i < Nn) ? cnt_i[i] : 0;
        // inclusive scan within wave
        int s = v;
        #pragma unroll
        for (int off = 1; off < 64; off <<= 1) {
            int t = __shfl_up(s, off, 64);
            if (lane >= off) s += t;
        }
        if (lane == 63) wsum[wid] = s;
        __syncthreads();
        if (tid < 16) {
            int si = wsum[tid];
            #pragma unroll
            for (int off = 1; off < 16; off <<= 1) {
                int t = __shfl_up(si, off, 64);
                if (tid >= off) si += t;
            }
            wsum[tid] = si;
        }
        __syncthreads();
        int base = carry + (wid > 0 ? wsum[wid - 1] : 0);
        int excl = base + s - v;
        if (i < Nn) { start[i] = excl; cursor[i] = excl; }
        int total = wsum[15];
        __syncthreads();
        carry += total;
    }
    if (tid == 0) start[Nn] = carry;
}

__global__ __launch_bounds__(256)
void k_fill(const int* __restrict__ colidx, int* __restrict__ cursor,
            int* __restrict__ elist, int E)
{
    int e = blockIdx.x * 256 + threadIdx.x;
    if (e < E) {
        int p = atomicAdd(&cursor[colidx[e]], 1);
        elist[p] = e;
    }
}

// ---------------------------------------------------------------------------
// Gather: one wave per node. agg[n,:] = mean_e(elu(bn(h[e,:]))) as f16.
// Lane l owns channels 2l, 2l+1. Inner loads pipelined 4-deep.
// ---------------------------------------------------------------------------
__global__ __launch_bounds__(256)
void gather_nodes(const f16* __restrict__ hbuf, const int* __restrict__ start,
                  const int* __restrict__ elist,
                  const float* __restrict__ scale, const float* __restrict__ shift,
                  f16* __restrict__ agg, int Nn)
{
    const int tid  = threadIdx.x;
    const int lane = tid & 63;
    const int wave = tid >> 6;
    const int node = blockIdx.x * 4 + wave;
    if (node >= Nn) return;

    const float sc0 = scale[2 * lane],  sc1 = scale[2 * lane + 1];
    const float sh0 = shift[2 * lane],  sh1 = shift[2 * lane + 1];
    const int s0 = start[node], s1 = start[node + 1];
    float a0 = 0.f, a1 = 0.f;

    for (int base = s0; base < s1; base += 64) {
        int e_l = (base + lane < s1) ? elist[base + lane] : 0;
        int m = s1 - base; if (m > 64) m = 64;
        for (int j = 0; j < m; j += 4) {
            f16x2 hv[4];
            #pragma unroll
            for (int k = 0; k < 4; ++k) {
                int jj = j + k; if (jj > m - 1) jj = m - 1;
                int e = __shfl(e_l, jj, 64);
                hv[k] = *(const f16x2*)&hbuf[(size_t)e * CC + 2 * lane];
            }
            #pragma unroll
            for (int k = 0; k < 4; ++k) {
                if (j + k < m) {
                    a0 += elu((float)hv[k].x * sc0 + sh0);
                    a1 += elu((float)hv[k].y * sc1 + sh1);
                }
            }
        }
    }
    const int deg = s1 - s0;
    const float inv = deg > 0 ? 1.f / (float)deg : 0.f;
    f16x2 o; o.x = (f16)(a0 * inv); o.y = (f16)(a1 * inv);
    *(f16x2*)&agg[(size_t)node * CC + 2 * lane] = o;
}

// ---------------------------------------------------------------------------
// Node GEMM: out_pre[i,:] = concat(x[i], agg[i]) @ w2.T + b2  (agg already f16, pre-divided)
// ---------------------------------------------------------------------------
__global__ __launch_bounds__(256)
void node_gemm(const float* __restrict__ x, const f16* __restrict__ agg,
               const float* __restrict__ w2, const float* __restrict__ b2,
               float* __restrict__ outp, float* __restrict__ sum2,
               float* __restrict__ sq2, int Nn, int nTiles)
{
    __shared__ __align__(16) f16 a_lds[32 * 264];
    __shared__ __align__(16) float f_lds[32 * 132];

    const int tid  = threadIdx.x;
    const int lane = tid & 63;
    const int wave = tid >> 6;
    const int quad = lane >> 4;
    const int l16  = lane & 15;
    const int n_off = wave * 32;

    f16x8 bfrag[8][2];
    float bias[2];
    #pragma unroll
    for (int ns = 0; ns < 2; ++ns) {
        int n = n_off + ns * 16 + l16;
        bias[ns] = b2[n];
        #pragma unroll
        for (int kk = 0; kk < 8; ++kk) {
            const float* wr = w2 + n * K2 + kk * 32 + quad * 8;
            f16x8 f;
            #pragma unroll
            for (int j = 0; j < 8; ++j) f[j] = (f16)wr[j];
            bfrag[kk][ns] = f;
        }
    }

    float st_s[2] = {0.f, 0.f};
    float st_q[2] = {0.f, 0.f};
    const f32x4 zero4 = {0.f, 0.f, 0.f, 0.f};

    for (int t = blockIdx.x; t < nTiles; t += gridDim.x) {
        const int i0 = t * 32;
        __syncthreads();

        #pragma unroll
        for (int i = 0; i < 8; ++i) {
            int chunk = tid + i * 256;
            int r  = chunk >> 6;
            int cc = (chunk & 63) * 4;
            int node = i0 + r;
            f16 tmp[4] = {(f16)0.f, (f16)0.f, (f16)0.f, (f16)0.f};
            if (node < Nn) {
                if (cc < CC) {
                    float4 v = *(const float4*)(x + (size_t)node * CC + cc);
                    tmp[0] = (f16)v.x; tmp[1] = (f16)v.y; tmp[2] = (f16)v.z; tmp[3] = (f16)v.w;
                } else {
                    *(f16x4*)tmp = *(const f16x4*)(agg + (size_t)node * CC + (cc - CC));
                }
            }
            *(f16x4*)&a_lds[r * 264 + cc] = *(f16x4*)tmp;
        }
        __syncthreads();

        f32x4 acc[2][2];
        acc[0][0] = zero4; acc[0][1] = zero4; acc[1][0] = zero4; acc[1][1] = zero4;

        #pragma unroll
        for (int kk = 0; kk < 8; ++kk) {
            int kb = kk * 32 + quad * 8;
            f16x8 af0 = *(f16x8*)&a_lds[l16 * 264 + kb];
            f16x8 af1 = *(f16x8*)&a_lds[(16 + l16) * 264 + kb];
            acc[0][0] = __builtin_amdgcn_mfma_f32_16x16x32_f16(af0, bfrag[kk][0], acc[0][0], 0, 0, 0);
            acc[0][1] = __builtin_amdgcn_mfma_f32_16x16x32_f16(af0, bfrag[kk][1], acc[0][1], 0, 0, 0);
            acc[1][0] = __builtin_amdgcn_mfma_f32_16x16x32_f16(af1, bfrag[kk][0], acc[1][0], 0, 0, 0);
            acc[1][1] = __builtin_amdgcn_mfma_f32_16x16x32_f16(af1, bfrag[kk][1], acc[1][1], 0, 0, 0);
        }

        #pragma unroll
        for (int ms = 0; ms < 2; ++ms) {
            #pragma unroll
            for (int ns = 0; ns < 2; ++ns) {
                int col = n_off + ns * 16 + l16;
                #pragma unroll
                for (int r = 0; r < 4; ++r) {
                    int rl = ms * 16 + quad * 4 + r;
                    float v = acc[ms][ns][r] + bias[ns];
                    if (i0 + rl < Nn) { st_s[ns] += v; st_q[ns] += v * v; }
                    f_lds[rl * 132 + col] = v;
                }
            }
        }
        __syncthreads();

        #pragma unroll
        for (int j = 0; j < 4; ++j) {
            int chunk = tid + j * 256;
            int r  = chunk >> 5;
            int cc = (chunk & 31) * 4;
            if (i0 + r < Nn) {
                float4 v = *(float4*)&f_lds[r * 132 + cc];
                *(float4*)&outp[(size_t)(i0 + r) * CC + cc] = v;
            }
        }
    }

    #pragma unroll
    for (int ns = 0; ns < 2; ++ns) {
        float s = st_s[ns], q = st_q[ns];
        s += __shfl_xor(s, 16, 64); q += __shfl_xor(q, 16, 64);
        s += __shfl_xor(s, 32, 64); q += __shfl_xor(q, 32, 64);
        if (lane < 16) {
            int c = n_off + ns * 16 + lane;
            atomicAdd(&sum2[c], s);
            atomicAdd(&sq2[c], q);
        }
    }
}

// ---------------------------------------------------------------------------
__global__ __launch_bounds__(256)
void bn_elu_out(float* __restrict__ out, const float* __restrict__ scale,
                const float* __restrict__ shift, int total4)
{
    int g = blockIdx.x * 256 + threadIdx.x;
    if (g >= total4) return;
    int cb = (g & 31) * 4;
    float4 v = ((const float4*)out)[g];
    v.x = elu(v.x * scale[cb + 0] + shift[cb + 0]);
    v.y = elu(v.y * scale[cb + 1] + shift[cb + 1]);
    v.z = elu(v.z * scale[cb + 2] + shift[cb + 2]);
    v.w = elu(v.w * scale[cb + 3] + shift[cb + 3]);
    ((float4*)out)[g] = v;
}

// ---------------------------------------------------------------------------
extern "C" void kernel_launch(void* const* d_in, const int* in_sizes, int n_in,
                              void* d_out, int out_size, void* d_ws, size_t ws_size,
                              hipStream_t stream)
{
    const float* x     = (const float*)d_in[0];
    const int*   eidx  = (const int*)d_in[1];
    const float* eattr = (const float*)d_in[2];
    // d_in[3] = u, d_in[4] = batch : unused by the reference
    const float* w1   = (const float*)d_in[5];
    const float* b1   = (const float*)d_in[6];
    const float* bn1w = (const float*)d_in[7];
    const float* bn1b = (const float*)d_in[8];
    const float* w2   = (const float*)d_in[9];
    const float* b2   = (const float*)d_in[10];
    const float* bn2w = (const float*)d_in[11];
    const float* bn2b = (const float*)d_in[12];

    const int Nn = in_sizes[0] / CC;   // 50000
    const int E  = in_sizes[1] / 2;    // 800000
    const int* rowi = eidx;
    const int* coli = eidx + E;

    char* ws = (char*)d_ws;
    size_t off = 0;
    f16* hbuf = (f16*)(ws + off);   off += (size_t)E * CC * sizeof(f16);     // 204.8 MB
    f16* agg  = (f16*)(ws + off);   off += (size_t)Nn * CC * sizeof(f16);    // 12.8 MB
    int* elist  = (int*)(ws + off); off += (size_t)E * sizeof(int);          // 3.2 MB
    int* cnt_i  = (int*)(ws + off); off += (size_t)Nn * sizeof(int);
    int* start  = (int*)(ws + off); off += (size_t)(Nn + 1) * sizeof(int);
    int* cursor = (int*)(ws + off); off += (size_t)Nn * sizeof(int);
    float* sum1 = (float*)(ws + off);
    float* sq1  = sum1 + CC;
    float* sc1  = sum1 + 2 * CC;
    float* sh1  = sum1 + 3 * CC;
    float* sum2 = sum1 + 4 * CC;
    float* sq2  = sum1 + 5 * CC;
    float* sc2  = sum1 + 6 * CC;
    float* sh2  = sum1 + 7 * CC;

    hipMemsetAsync(cnt_i, 0, (size_t)Nn * sizeof(int), stream);
    hipMemsetAsync(sum1, 0, 8 * CC * sizeof(float), stream);

    // CSR build (independent of edge_gemm, but stream-serialized anyway)
    const int nBe = (E + 255) / 256;
    k_hist<<<nBe, 256, 0, stream>>>(coli, cnt_i, E);
    k_scan<<<1, 1024, 0, stream>>>(cnt_i, start, cursor, Nn);
    k_fill<<<nBe, 256, 0, stream>>>(coli, cursor, elist, E);

    const int nT1 = (E + 31) / 32;
    edge_gemm<<<1024, 256, 0, stream>>>(x, rowi, eattr, w1, b1, hbuf, sum1, sq1, E, nT1);
    finalize_stats<<<1, CC, 0, stream>>>(sum1, sq1, bn1w, bn1b, sc1, sh1, 1.f / (float)E);

    gather_nodes<<<(Nn + 3) / 4, 256, 0, stream>>>(hbuf, start, elist, sc1, sh1, agg, Nn);

    const int nT2 = (Nn + 31) / 32;
    node_gemm<<<nT2, 256, 0, stream>>>(x, agg, w2, b2, (float*)d_out, sum2, sq2, Nn, nT2);
    finalize_stats<<<1, CC, 0, stream>>>(sum2, sq2, bn2w, bn2b, sc2, sh2, 1.f / (float)Nn);

    const int t4 = Nn * CC / 4;
    bn_elu_out<<<(t4 + 255) / 256, 256, 0, stream>>>((float*)d_out, sc2, sh2, t4);
}

// Round 3
// 969.428 us; speedup vs baseline: 3.7774x; 1.1447x over previous
//
#include <hip/hip_runtime.h>

typedef _Float16 f16;
typedef __attribute__((ext_vector_type(8))) _Float16 f16x8;
typedef __attribute__((ext_vector_type(4))) _Float16 f16x4;
typedef __attribute__((ext_vector_type(2))) _Float16 f16x2;
typedef __attribute__((ext_vector_type(4))) float f32x4;

#define CC 128
#define K2 256
#define BN_EPS 1e-5f

__device__ __forceinline__ float elu(float v) {
    return v > 0.f ? v : __expf(v) - 1.f;
}

// ---------------------------------------------------------------------------
// Edge GEMM: h[e,:] = concat(x[row[e]], edge_attr[e]) @ w1.T + b1
// Register-prefetch software pipeline: tile t+1's global loads are issued
// right after tile t's A-barrier and consumed at the next LDS-write, so HBM
// latency overlaps MFMA + h-store. Lanes 0-31 load the x-half (via rowidx),
// lanes 32-63 the eattr-half; each wave stages rows {wave+4i}.
// ---------------------------------------------------------------------------
__global__ __launch_bounds__(256, 3)
void edge_gemm(const float* __restrict__ x, const int* __restrict__ rowidx,
               const float* __restrict__ eattr, const float* __restrict__ w1,
               const float* __restrict__ b1,
               f16* __restrict__ hbuf, float* __restrict__ sum1,
               float* __restrict__ sq1, int E, int nTiles)
{
    __shared__ __align__(16) f16 a_lds[32 * 264];   // 32 rows x 256 f16, +8 pad
    __shared__ __align__(16) f16 h_lds[32 * 136];   // 32 rows x 128 f16, +8 pad

    const int tid  = threadIdx.x;
    const int lane = tid & 63;
    const int wave = tid >> 6;
    const int quad = lane >> 4;
    const int l16  = lane & 15;
    const int n_off = wave * 32;
    const bool is_x = lane < 32;

    // Preload B fragments: B[k][n] = w1[n][k]  (w1 is [128][256] row-major)
    f16x8 bfrag[8][2];
    float bias[2];
    #pragma unroll
    for (int ns = 0; ns < 2; ++ns) {
        int n = n_off + ns * 16 + l16;
        bias[ns] = b1[n];
        #pragma unroll
        for (int kk = 0; kk < 8; ++kk) {
            const float* wr = w1 + n * K2 + kk * 32 + quad * 8;
            f16x8 f;
            #pragma unroll
            for (int j = 0; j < 8; ++j) f[j] = (f16)wr[j];
            bfrag[kk][ns] = f;
        }
    }

    float st_s[2] = {0.f, 0.f};
    float st_q[2] = {0.f, 0.f};
    const f32x4 zero4 = {0.f, 0.f, 0.f, 0.f};

    float4 pre[8];   // prefetched A rows (raw fp32; cvt deferred to LDS write)

    auto issue_prefetch = [&](int t) {
        const int e0 = t * 32;
        int ridx[8];
        #pragma unroll
        for (int i = 0; i < 8; ++i) {
            int e = e0 + wave + i * 4;
            if (e > E - 1) e = E - 1;
            ridx[i] = rowidx[e];
        }
        #pragma unroll
        for (int i = 0; i < 8; ++i) {
            int e = e0 + wave + i * 4;
            if (e > E - 1) e = E - 1;
            const float* src = is_x
                ? x + (size_t)ridx[i] * CC + lane * 4
                : eattr + (size_t)e * CC + (lane * 4 - CC);
            pre[i] = *(const float4*)src;
        }
    };

    int t0 = blockIdx.x;
    if (t0 < nTiles) issue_prefetch(t0);

    for (int t = t0; t < nTiles; t += gridDim.x) {
        const int e0 = t * 32;

        // pre (tile t) -> a_lds, with fp32->f16 conversion
        #pragma unroll
        for (int i = 0; i < 8; ++i) {
            int r = wave + i * 4;
            f16 tmp[4] = {(f16)pre[i].x, (f16)pre[i].y, (f16)pre[i].z, (f16)pre[i].w};
            *(f16x4*)&a_lds[r * 264 + lane * 4] = *(f16x4*)tmp;
        }
        __syncthreads();

        // issue next tile's loads (consumed at next iteration's LDS write)
        int tn = t + gridDim.x;
        if (tn < nTiles) issue_prefetch(tn);

        f32x4 acc[2][2];
        acc[0][0] = zero4; acc[0][1] = zero4; acc[1][0] = zero4; acc[1][1] = zero4;

        #pragma unroll
        for (int kk = 0; kk < 8; ++kk) {
            int kb = kk * 32 + quad * 8;
            f16x8 af0 = *(f16x8*)&a_lds[l16 * 264 + kb];
            f16x8 af1 = *(f16x8*)&a_lds[(16 + l16) * 264 + kb];
            acc[0][0] = __builtin_amdgcn_mfma_f32_16x16x32_f16(af0, bfrag[kk][0], acc[0][0], 0, 0, 0);
            acc[0][1] = __builtin_amdgcn_mfma_f32_16x16x32_f16(af0, bfrag[kk][1], acc[0][1], 0, 0, 0);
            acc[1][0] = __builtin_amdgcn_mfma_f32_16x16x32_f16(af1, bfrag[kk][0], acc[1][0], 0, 0, 0);
            acc[1][1] = __builtin_amdgcn_mfma_f32_16x16x32_f16(af1, bfrag[kk][1], acc[1][1], 0, 0, 0);
        }

        // Bias + stats + stage h tile into LDS (C/D layout: col=lane&15, row=quad*4+reg)
        #pragma unroll
        for (int ms = 0; ms < 2; ++ms) {
            #pragma unroll
            for (int ns = 0; ns < 2; ++ns) {
                int col = n_off + ns * 16 + l16;
                #pragma unroll
                for (int r = 0; r < 4; ++r) {
                    int rl = ms * 16 + quad * 4 + r;
                    float v = acc[ms][ns][r] + bias[ns];
                    if (e0 + rl < E) { st_s[ns] += v; st_q[ns] += v * v; }
                    h_lds[rl * 136 + col] = (f16)v;
                }
            }
        }
        __syncthreads();

        // Coalesced store of the h tile (f16x8 per thread x2)
        #pragma unroll
        for (int j = 0; j < 2; ++j) {
            int chunk = tid + j * 256;
            int r  = chunk >> 4;
            int cc = (chunk & 15) * 8;
            if (e0 + r < E) {
                f16x8 v = *(f16x8*)&h_lds[r * 136 + cc];
                *(f16x8*)&hbuf[(size_t)(e0 + r) * CC + cc] = v;
            }
        }
        __syncthreads();
    }

    // Reduce stats across quads, one atomic per channel per wave
    #pragma unroll
    for (int ns = 0; ns < 2; ++ns) {
        float s = st_s[ns], q = st_q[ns];
        s += __shfl_xor(s, 16, 64); q += __shfl_xor(q, 16, 64);
        s += __shfl_xor(s, 32, 64); q += __shfl_xor(q, 32, 64);
        if (lane < 16) {
            int c = n_off + ns * 16 + lane;
            atomicAdd(&sum1[c], s);
            atomicAdd(&sq1[c], q);
        }
    }
}

// ---------------------------------------------------------------------------
__global__ void finalize_stats(const float* __restrict__ sum, const float* __restrict__ sq,
                               const float* __restrict__ bnw, const float* __restrict__ bnb,
                               float* __restrict__ scale, float* __restrict__ shift,
                               float invN)
{
    int c = threadIdx.x;
    float mu  = sum[c] * invN;
    float var = sq[c] * invN - mu * mu;
    float sc  = bnw[c] * rsqrtf(var + BN_EPS);
    scale[c] = sc;
    shift[c] = bnb[c] - mu * sc;
}

// ---------------------------------------------------------------------------
// CSR build: histogram -> single-block scan -> fill
// ---------------------------------------------------------------------------
__global__ __launch_bounds__(256)
void k_hist(const int* __restrict__ colidx, int* __restrict__ cnt_i, int E)
{
    int e = blockIdx.x * 256 + threadIdx.x;
    if (e < E) atomicAdd(&cnt_i[colidx[e]], 1);
}

__global__ __launch_bounds__(1024)
void k_scan(const int* __restrict__ cnt_i, int* __restrict__ start,
            int* __restrict__ cursor, int Nn)
{
    __shared__ int wsum[16];
    const int tid  = threadIdx.x;
    const int lane = tid & 63;
    const int wid  = tid >> 6;
    int carry = 0;
    const int nChunks = (Nn + 1023) / 1024;
    for (int c = 0; c < nChunks; ++c) {
        int i = c * 1024 + tid;
        int v = (i < Nn) ? cnt_i[i] : 0;
        int s = v;
        #pragma unroll
        for (int off = 1; off < 64; off <<= 1) {
            int t = __shfl_up(s, off, 64);
            if (lane >= off) s += t;
        }
        if (lane == 63) wsum[wid] = s;
        __syncthreads();
        if (tid < 16) {
            int si = wsum[tid];
            #pragma unroll
            for (int off = 1; off < 16; off <<= 1) {
                int t = __shfl_up(si, off, 64);
                if (tid >= off) si += t;
            }
            wsum[tid] = si;
        }
        __syncthreads();
        int base = carry + (wid > 0 ? wsum[wid - 1] : 0);
        int excl = base + s - v;
        if (i < Nn) { start[i] = excl; cursor[i] = excl; }
        int total = wsum[15];
        __syncthreads();
        carry += total;
    }
    if (tid == 0) start[Nn] = carry;
}

__global__ __launch_bounds__(256)
void k_fill(const int* __restrict__ colidx, int* __restrict__ cursor,
            int* __restrict__ elist, int E)
{
    int e = blockIdx.x * 256 + threadIdx.x;
    if (e < E) {
        int p = atomicAdd(&cursor[colidx[e]], 1);
        elist[p] = e;
    }
}

// ---------------------------------------------------------------------------
// Gather: one wave per node, half-wave per edge (32 lanes x f16x4 = 256 B).
// 2 edges per step x 4-deep pipeline = 8 edge-rows in flight per wave.
// agg[n,:] = mean_e(elu(bn(h[e,:]))) as f16.
// ---------------------------------------------------------------------------
__global__ __launch_bounds__(256)
void gather_nodes(const f16* __restrict__ hbuf, const int* __restrict__ start,
                  const int* __restrict__ elist,
                  const float* __restrict__ scale, const float* __restrict__ shift,
                  f16* __restrict__ agg, int Nn)
{
    const int tid  = threadIdx.x;
    const int lane = tid & 63;
    const int wave = tid >> 6;
    const int node = blockIdx.x * 4 + wave;
    if (node >= Nn) return;

    const int half = lane >> 5;        // which edge of the pair
    const int cb   = (lane & 31) * 4;  // channel base (4 channels per lane)

    float sc[4], sh[4];
    #pragma unroll
    for (int c = 0; c < 4; ++c) { sc[c] = scale[cb + c]; sh[c] = shift[cb + c]; }

    const int s0 = start[node], s1 = start[node + 1];
    float a[4] = {0.f, 0.f, 0.f, 0.f};

    for (int base = s0; base < s1; base += 64) {
        int m = s1 - base; if (m > 64) m = 64;
        int e_l = elist[base + (lane < m ? lane : m - 1)];
        for (int j = 0; j < m; j += 8) {
            f16x4 hv[4];
            float va[4];
            #pragma unroll
            for (int k = 0; k < 4; ++k) {
                int idx = j + 2 * k + half;
                va[k] = (idx < m) ? 1.f : 0.f;
                int ii = (idx < m) ? idx : m - 1;
                int e = __shfl(e_l, ii, 64);
                hv[k] = *(const f16x4*)&hbuf[(size_t)e * CC + cb];
            }
            #pragma unroll
            for (int k = 0; k < 4; ++k) {
                #pragma unroll
                for (int c = 0; c < 4; ++c)
                    a[c] += va[k] * elu((float)hv[k][c] * sc[c] + sh[c]);
            }
        }
    }

    #pragma unroll
    for (int c = 0; c < 4; ++c) a[c] += __shfl_xor(a[c], 32, 64);

    if (half == 0) {
        const int deg = s1 - s0;
        const float inv = deg > 0 ? 1.f / (float)deg : 0.f;
        f16x4 o;
        #pragma unroll
        for (int c = 0; c < 4; ++c) o[c] = (f16)(a[c] * inv);
        *(f16x4*)&agg[(size_t)node * CC + cb] = o;
    }
}

// ---------------------------------------------------------------------------
// Node GEMM: out_pre[i,:] = concat(x[i], agg[i]) @ w2.T + b2  (agg f16, pre-divided)
// ---------------------------------------------------------------------------
__global__ __launch_bounds__(256)
void node_gemm(const float* __restrict__ x, const f16* __restrict__ agg,
               const float* __restrict__ w2, const float* __restrict__ b2,
               float* __restrict__ outp, float* __restrict__ sum2,
               float* __restrict__ sq2, int Nn, int nTiles)
{
    __shared__ __align__(16) f16 a_lds[32 * 264];
    __shared__ __align__(16) float f_lds[32 * 132];

    const int tid  = threadIdx.x;
    const int lane = tid & 63;
    const int wave = tid >> 6;
    const int quad = lane >> 4;
    const int l16  = lane & 15;
    const int n_off = wave * 32;

    f16x8 bfrag[8][2];
    float bias[2];
    #pragma unroll
    for (int ns = 0; ns < 2; ++ns) {
        int n = n_off + ns * 16 + l16;
        bias[ns] = b2[n];
        #pragma unroll
        for (int kk = 0; kk < 8; ++kk) {
            const float* wr = w2 + n * K2 + kk * 32 + quad * 8;
            f16x8 f;
            #pragma unroll
            for (int j = 0; j < 8; ++j) f[j] = (f16)wr[j];
            bfrag[kk][ns] = f;
        }
    }

    float st_s[2] = {0.f, 0.f};
    float st_q[2] = {0.f, 0.f};
    const f32x4 zero4 = {0.f, 0.f, 0.f, 0.f};

    for (int t = blockIdx.x; t < nTiles; t += gridDim.x) {
        const int i0 = t * 32;
        __syncthreads();

        #pragma unroll
        for (int i = 0; i < 8; ++i) {
            int chunk = tid + i * 256;
            int r  = chunk >> 6;
            int cc = (chunk & 63) * 4;
            int node = i0 + r;
            f16 tmp[4] = {(f16)0.f, (f16)0.f, (f16)0.f, (f16)0.f};
            if (node < Nn) {
                if (cc < CC) {
                    float4 v = *(const float4*)(x + (size_t)node * CC + cc);
                    tmp[0] = (f16)v.x; tmp[1] = (f16)v.y; tmp[2] = (f16)v.z; tmp[3] = (f16)v.w;
                } else {
                    *(f16x4*)tmp = *(const f16x4*)(agg + (size_t)node * CC + (cc - CC));
                }
            }
            *(f16x4*)&a_lds[r * 264 + cc] = *(f16x4*)tmp;
        }
        __syncthreads();

        f32x4 acc[2][2];
        acc[0][0] = zero4; acc[0][1] = zero4; acc[1][0] = zero4; acc[1][1] = zero4;

        #pragma unroll
        for (int kk = 0; kk < 8; ++kk) {
            int kb = kk * 32 + quad * 8;
            f16x8 af0 = *(f16x8*)&a_lds[l16 * 264 + kb];
            f16x8 af1 = *(f16x8*)&a_lds[(16 + l16) * 264 + kb];
            acc[0][0] = __builtin_amdgcn_mfma_f32_16x16x32_f16(af0, bfrag[kk][0], acc[0][0], 0, 0, 0);
            acc[0][1] = __builtin_amdgcn_mfma_f32_16x16x32_f16(af0, bfrag[kk][1], acc[0][1], 0, 0, 0);
            acc[1][0] = __builtin_amdgcn_mfma_f32_16x16x32_f16(af1, bfrag[kk][0], acc[1][0], 0, 0, 0);
            acc[1][1] = __builtin_amdgcn_mfma_f32_16x16x32_f16(af1, bfrag[kk][1], acc[1][1], 0, 0, 0);
        }

        #pragma unroll
        for (int ms = 0; ms < 2; ++ms) {
            #pragma unroll
            for (int ns = 0; ns < 2; ++ns) {
                int col = n_off + ns * 16 + l16;
                #pragma unroll
                for (int r = 0; r < 4; ++r) {
                    int rl = ms * 16 + quad * 4 + r;
                    float v = acc[ms][ns][r] + bias[ns];
                    if (i0 + rl < Nn) { st_s[ns] += v; st_q[ns] += v * v; }
                    f_lds[rl * 132 + col] = v;
                }
            }
        }
        __syncthreads();

        #pragma unroll
        for (int j = 0; j < 4; ++j) {
            int chunk = tid + j * 256;
            int r  = chunk >> 5;
            int cc = (chunk & 31) * 4;
            if (i0 + r < Nn) {
                float4 v = *(float4*)&f_lds[r * 132 + cc];
                *(float4*)&outp[(size_t)(i0 + r) * CC + cc] = v;
            }
        }
    }

    #pragma unroll
    for (int ns = 0; ns < 2; ++ns) {
        float s = st_s[ns], q = st_q[ns];
        s += __shfl_xor(s, 16, 64); q += __shfl_xor(q, 16, 64);
        s += __shfl_xor(s, 32, 64); q += __shfl_xor(q, 32, 64);
        if (lane < 16) {
            int c = n_off + ns * 16 + lane;
            atomicAdd(&sum2[c], s);
            atomicAdd(&sq2[c], q);
        }
    }
}

// ---------------------------------------------------------------------------
__global__ __launch_bounds__(256)
void bn_elu_out(float* __restrict__ out, const float* __restrict__ scale,
                const float* __restrict__ shift, int total4)
{
    int g = blockIdx.x * 256 + threadIdx.x;
    if (g >= total4) return;
    int cb = (g & 31) * 4;
    float4 v = ((const float4*)out)[g];
    v.x = elu(v.x * scale[cb + 0] + shift[cb + 0]);
    v.y = elu(v.y * scale[cb + 1] + shift[cb + 1]);
    v.z = elu(v.z * scale[cb + 2] + shift[cb + 2]);
    v.w = elu(v.w * scale[cb + 3] + shift[cb + 3]);
    ((float4*)out)[g] = v;
}

// ---------------------------------------------------------------------------
extern "C" void kernel_launch(void* const* d_in, const int* in_sizes, int n_in,
                              void* d_out, int out_size, void* d_ws, size_t ws_size,
                              hipStream_t stream)
{
    const float* x     = (const float*)d_in[0];
    const int*   eidx  = (const int*)d_in[1];
    const float* eattr = (const float*)d_in[2];
    // d_in[3] = u, d_in[4] = batch : unused by the reference
    const float* w1   = (const float*)d_in[5];
    const float* b1   = (const float*)d_in[6];
    const float* bn1w = (const float*)d_in[7];
    const float* bn1b = (const float*)d_in[8];
    const float* w2   = (const float*)d_in[9];
    const float* b2   = (const float*)d_in[10];
    const float* bn2w = (const float*)d_in[11];
    const float* bn2b = (const float*)d_in[12];

    const int Nn = in_sizes[0] / CC;   // 50000
    const int E  = in_sizes[1] / 2;    // 800000
    const int* rowi = eidx;
    const int* coli = eidx + E;

    char* ws = (char*)d_ws;
    size_t off = 0;
    f16* hbuf = (f16*)(ws + off);   off += (size_t)E * CC * sizeof(f16);     // 204.8 MB
    f16* agg  = (f16*)(ws + off);   off += (size_t)Nn * CC * sizeof(f16);    // 12.8 MB
    int* elist  = (int*)(ws + off); off += (size_t)E * sizeof(int);          // 3.2 MB
    int* cnt_i  = (int*)(ws + off); off += (size_t)Nn * sizeof(int);
    int* start  = (int*)(ws + off); off += (size_t)(Nn + 1) * sizeof(int);
    int* cursor = (int*)(ws + off); off += (size_t)Nn * sizeof(int);
    float* sum1 = (float*)(ws + off);
    float* sq1  = sum1 + CC;
    float* sc1  = sum1 + 2 * CC;
    float* sh1  = sum1 + 3 * CC;
    float* sum2 = sum1 + 4 * CC;
    float* sq2  = sum1 + 5 * CC;
    float* sc2  = sum1 + 6 * CC;
    float* sh2  = sum1 + 7 * CC;

    hipMemsetAsync(cnt_i, 0, (size_t)Nn * sizeof(int), stream);
    hipMemsetAsync(sum1, 0, 8 * CC * sizeof(float), stream);

    // CSR build
    const int nBe = (E + 255) / 256;
    k_hist<<<nBe, 256, 0, stream>>>(coli, cnt_i, E);
    k_scan<<<1, 1024, 0, stream>>>(cnt_i, start, cursor, Nn);
    k_fill<<<nBe, 256, 0, stream>>>(coli, cursor, elist, E);

    const int nT1 = (E + 31) / 32;
    edge_gemm<<<2048, 256, 0, stream>>>(x, rowi, eattr, w1, b1, hbuf, sum1, sq1, E, nT1);
    finalize_stats<<<1, CC, 0, stream>>>(sum1, sq1, bn1w, bn1b, sc1, sh1, 1.f / (float)E);

    gather_nodes<<<(Nn + 3) / 4, 256, 0, stream>>>(hbuf, start, elist, sc1, sh1, agg, Nn);

    const int nT2 = (Nn + 31) / 32;
    node_gemm<<<nT2, 256, 0, stream>>>(x, agg, w2, b2, (float*)d_out, sum2, sq2, Nn, nT2);
    finalize_stats<<<1, CC, 0, stream>>>(sum2, sq2, bn2w, bn2b, sc2, sh2, 1.f / (float)Nn);

    const int t4 = Nn * CC / 4;
    bn_elu_out<<<(t4 + 255) / 256, 256, 0, stream>>>((float*)d_out, sc2, sh2, t4);
}